// Round 1
// 823.228 us; speedup vs baseline: 1.1809x; 1.1809x over previous
//
#include <hip/hip_runtime.h>

#define S_SEG 2048
#define C_ALL 64
#define P_PIX (1024 * 1024)

// ============================================================================
// NEW PATH: counting-sort pipeline (no scatter fp32 LDS atomics).
// Theory: old accum_kernel was bound by LDS atomic serialization
// (~3.3 cyc per lane ds_add_f32, measured), floor ~312us. This path replaces
// 80M scatter atomics with streaming: count -> prefix -> scatter rows of 256B
// -> register accumulation per segment.
// ============================================================================

#define NQ 4                       // pixel quarters (64 MB bounce buffer, LLC-resident)
#define PQ (P_PIX / NQ)            // 262144 pixels per quarter
#define FS_WORDS (PQ * C_ALL)      // featsS: [PQ][64] f32 = 64 MB

// ws word offsets (4-byte units)
#define W_SUM  FS_WORDS                       // float [2048*64]  (zeroed)
#define W_SQ   (W_SUM + S_SEG * C_ALL)        // float [2048]     (zeroed)
#define W_CNTQ (W_SQ + S_SEG)                 // int   [4*2048]   (zeroed)
#define W_CNTT (W_CNTQ + NQ * S_SEG)          // int   [2048]     (written by prefix)
#define W_OFF  (W_CNTT + S_SEG)               // int   [4*2048]   (written by prefix)
#define W_CUR  (W_OFF + NQ * S_SEG)           // int   [4*2048]   (written by prefix)
#define W_END  (W_CUR + NQ * S_SEG)
#define ZERO2_WORDS (S_SEG * C_ALL + S_SEG + NQ * S_SEG)   // sum_sc + sq_s + cnt_q
#define NEEDED_BYTES ((size_t)W_END * 4)

#define SC_CHUNK 512               // pixels per scatter block
#define SC_THREADS 512
#define SC_BLOCKS (PQ / SC_CHUNK)  // 512

__global__ void zero_kernel(float* __restrict__ p, int n) {
    int i = blockIdx.x * blockDim.x + threadIdx.x;
    if (i < n) p[i] = 0.0f;  // bit pattern 0 also zeroes int regions
}

// per-quarter segment counts. 256 blocks x 4096 px; block b -> quarter b/64.
__global__ __launch_bounds__(256) void countq_kernel(const int* __restrict__ sp,
                                                     int* __restrict__ cnt_q) {
    __shared__ int h[S_SEG];
    const int tid = threadIdx.x;
    for (int i = tid; i < S_SEG; i += 256) h[i] = 0;
    __syncthreads();
    const int base = blockIdx.x * 4096;
    const int4* sp4 = (const int4*)(sp + base);
    for (int it = 0; it < 4; ++it) {
        const int4 s4 = sp4[it * 256 + tid];
        atomicAdd(&h[s4.x], 1);
        atomicAdd(&h[s4.y], 1);
        atomicAdd(&h[s4.z], 1);
        atomicAdd(&h[s4.w], 1);
    }
    __syncthreads();
    int* dst = cnt_q + (blockIdx.x >> 6) * S_SEG;
    for (int i = tid; i < S_SEG; i += 256) {
        const int v = h[i];
        if (v != 0) atomicAdd(&dst[i], v);
    }
}

// single block: totals + per-quarter exclusive prefix (Hillis-Steele, dbuf).
__global__ __launch_bounds__(1024) void prefix_kernel(const int* __restrict__ cnt_q,
                                                      int* __restrict__ cnt_tot,
                                                      int* __restrict__ off_q,
                                                      int* __restrict__ cur_q) {
    __shared__ int a[S_SEG], b[S_SEG];
    const int tid = threadIdx.x;
    for (int i = tid; i < S_SEG; i += 1024) {
        int t = 0;
        for (int q = 0; q < NQ; ++q) t += cnt_q[q * S_SEG + i];
        cnt_tot[i] = t;
    }
    for (int q = 0; q < NQ; ++q) {
        for (int i = tid; i < S_SEG; i += 1024) a[i] = cnt_q[q * S_SEG + i];
        __syncthreads();
        int* src = a;
        int* dst = b;
        for (int d = 1; d < S_SEG; d <<= 1) {
            for (int i = tid; i < S_SEG; i += 1024)
                dst[i] = src[i] + (i >= d ? src[i - d] : 0);
            __syncthreads();
            int* t = src; src = dst; dst = t;
        }
        for (int i = tid; i < S_SEG; i += 1024) {
            const int e = i ? src[i - 1] : 0;
            off_q[q * S_SEG + i] = e;
            cur_q[q * S_SEG + i] = e;
        }
        __syncthreads();  // protect a/b before next quarter reloads
    }
}

// scatter: per block, 512 pixels of quarter q. Local LDS rank + per-segment
// global range reservation, then LDS-transposed feats tile -> contiguous
// 256 B row stores into featsS[pos][0..63]. No fp atomics.
__global__ __launch_bounds__(SC_THREADS) void scatter_kernel(
        const int* __restrict__ sp, const float* __restrict__ feats,
        int* __restrict__ cur_q, float* __restrict__ featsS, int q) {
    __shared__ int lh[S_SEG];                 // 8 KB: count -> global base -> cursor
    __shared__ int lpos[SC_CHUNK];            // 2 KB
    __shared__ float tile[C_ALL][129];        // 33 KB, pad 129 -> conflict-free columns
    const int tid = threadIdx.x;
    const int pixbase = q * PQ + blockIdx.x * SC_CHUNK;

    for (int i = tid; i < S_SEG; i += SC_THREADS) lh[i] = 0;
    __syncthreads();
    const int seg = sp[pixbase + tid];        // one pixel per thread
    atomicAdd(&lh[seg], 1);
    __syncthreads();
    int* cur = cur_q + q * S_SEG;
    for (int i = tid; i < S_SEG; i += SC_THREADS) {
        const int c = lh[i];
        if (c != 0) lh[i] = atomicAdd(&cur[i], c);  // reserve [base, base+c)
    }
    __syncthreads();
    lpos[tid] = atomicAdd(&lh[seg], 1);       // unique quarter-local slot
    __syncthreads();

    const int wave = tid >> 6, lane = tid & 63;
    for (int t0 = 0; t0 < SC_CHUNK; t0 += 128) {
        // stage [64][128] tile: coalesced float4 global loads, scalar LDS stores
        for (int k = tid; k < 2048; k += SC_THREADS) {
            const int c = k >> 5;
            const int x = (k & 31) << 2;
            const float4 v = *(const float4*)(feats + (size_t)c * P_PIX + pixbase + t0 + x);
            tile[c][x + 0] = v.x; tile[c][x + 1] = v.y;
            tile[c][x + 2] = v.z; tile[c][x + 3] = v.w;
        }
        __syncthreads();
        for (int t = wave; t < 128; t += 8) {
            const int p = lpos[t0 + t];                       // uniform per wave
            featsS[(size_t)p * 64 + lane] = tile[lane][t];    // 256 B contiguous store
        }
        __syncthreads();
    }
}

// per-segment register accumulation: lane = channel, rows contiguous in featsS.
__global__ __launch_bounds__(256) void accumq_kernel(
        const float* __restrict__ featsS, const int* __restrict__ cnt_q,
        const int* __restrict__ off_q, float* __restrict__ sum_sc,
        float* __restrict__ sq_s, int q) {
    const int seg = blockIdx.x;
    const int n = cnt_q[q * S_SEG + seg];
    if (n == 0) return;
    const int start = off_q[q * S_SEG + seg];
    const int wave = threadIdx.x >> 6, lane = threadIdx.x & 63;
    const float* base = featsS + (size_t)start * 64 + lane;
    float a0 = 0.f, a1 = 0.f, s0 = 0.f, s1 = 0.f;
    int i = wave;
    for (; i + 4 < n; i += 8) {
        const float v0 = base[(size_t)i * 64];
        const float v1 = base[(size_t)(i + 4) * 64];
        a0 += v0; s0 = fmaf(v0, v0, s0);
        a1 += v1; s1 = fmaf(v1, v1, s1);
    }
    for (; i < n; i += 4) {
        const float v = base[(size_t)i * 64];
        a0 += v; s0 = fmaf(v, v, s0);
    }
    __shared__ float pr[4][64];
    __shared__ float psq[4];
    pr[wave][lane] = a0 + a1;
    float sq = s0 + s1;
    for (int off = 32; off; off >>= 1) sq += __shfl_down(sq, off);
    if (lane == 0) psq[wave] = sq;
    __syncthreads();
    if (wave == 0) {
        const float tot = pr[0][lane] + pr[1][lane] + pr[2][lane] + pr[3][lane];
        sum_sc[(size_t)seg * 64 + lane] += tot;   // stream-ordered across quarters
        if (lane == 0) sq_s[seg] += psq[0] + psq[1] + psq[2] + psq[3];
    }
}

__global__ __launch_bounds__(1024) void finalizeq_kernel(
        const float* __restrict__ sum_sc, const float* __restrict__ sq_s,
        const int* __restrict__ cnt_tot, float* __restrict__ out) {
    __shared__ float red_l[16], red_c[16];
    const int tid = threadIdx.x;
    float loss = 0.0f, cc = 0.0f;
#pragma unroll
    for (int k = 0; k < 2; ++k) {
        const int s = tid + k * 1024;
        const float cnt = (float)cnt_tot[s];
        const float n = fmaxf(cnt, 1.0f);
        const float4* r = (const float4*)(sum_sc + (size_t)s * 64);
        float acc = 0.0f;
#pragma unroll
        for (int c4 = 0; c4 < 16; ++c4) {
            const float4 v = r[c4];
            acc = fmaf(v.x, v.x, acc);
            acc = fmaf(v.y, v.y, acc);
            acc = fmaf(v.z, v.z, acc);
            acc = fmaf(v.w, v.w, acc);
        }
        const float var = sq_s[s] - acc / n;
        loss += (cnt >= 2.0f) ? var / (64.0f * n) : 0.0f;
        cc += (cnt > 0.0f) ? 1.0f : 0.0f;
    }
    for (int off = 32; off; off >>= 1) {
        loss += __shfl_down(loss, off);
        cc += __shfl_down(cc, off);
    }
    const int wave = tid >> 6;
    if ((tid & 63) == 0) { red_l[wave] = loss; red_c[wave] = cc; }
    __syncthreads();
    if (tid < 16) {
        loss = red_l[tid]; cc = red_c[tid];
        for (int off = 8; off; off >>= 1) {
            loss += __shfl_down(loss, off);
            cc += __shfl_down(cc, off);
        }
        if (tid == 0) out[0] = loss / cc;
    }
}

// ============================================================================
// OLD PATH (fallback if ws too small): verified 972us LDS-atomic version.
// ============================================================================

#define CH_PER 4
#define N_GROUPS 16
#define N_CHUNKS 64
#define BLOCK 512
#define PIX_PER_BLOCK (P_PIX / N_CHUNKS)
#define OFF_SQ   131072
#define OFF_CNT  133120
#define N_ZERO   135168

__global__ __launch_bounds__(256) void count_kernel(const int* __restrict__ sp,
                                                    int* __restrict__ cnt_g) {
    __shared__ int cnt_h[S_SEG];
    const int tid = threadIdx.x;
    for (int i = tid; i < S_SEG; i += 256) cnt_h[i] = 0;
    __syncthreads();
    const int base = blockIdx.x * (P_PIX / 256);
    const int4* sp4 = (const int4*)(sp + base);
    const int iters = (P_PIX / 256) / (256 * 4);
    for (int it = 0; it < iters; ++it) {
        const int4 s4 = sp4[it * 256 + tid];
        atomicAdd(&cnt_h[s4.x], 1);
        atomicAdd(&cnt_h[s4.y], 1);
        atomicAdd(&cnt_h[s4.z], 1);
        atomicAdd(&cnt_h[s4.w], 1);
    }
    __syncthreads();
    for (int i = tid; i < S_SEG; i += 256) {
        const int v = cnt_h[i];
        if (v != 0) atomicAdd(&cnt_g[i], v);
    }
}

__global__ __launch_bounds__(BLOCK) void accum_kernel(
        const int* __restrict__ sp, const float* __restrict__ feats,
        float* __restrict__ sum_g, float* __restrict__ sq_g) {
    __shared__ float hist[CH_PER * S_SEG];
    __shared__ float sq_h[S_SEG];
    const int tid = threadIdx.x;
    const int chunk = blockIdx.x;
    const int grp = blockIdx.y;
    const int c0 = grp * CH_PER;

    for (int i = tid; i < CH_PER * S_SEG; i += BLOCK) hist[i] = 0.0f;
    for (int i = tid; i < S_SEG; i += BLOCK) sq_h[i] = 0.0f;
    __syncthreads();

    const int base = chunk * PIX_PER_BLOCK;
    const int4* sp4 = (const int4*)(sp + base);
    const int iters = PIX_PER_BLOCK / (BLOCK * 4);

    for (int it = 0; it < iters; ++it) {
        const int idx = it * BLOCK + tid;
        const int4 s4 = sp4[idx];
        float sq0 = 0.f, sq1 = 0.f, sq2 = 0.f, sq3 = 0.f;
#pragma unroll
        for (int c = 0; c < CH_PER; ++c) {
            const float4 v =
                ((const float4*)(feats + (size_t)(c0 + c) * P_PIX + base))[idx];
            unsafeAtomicAdd(&hist[c * S_SEG + s4.x], v.x); sq0 = fmaf(v.x, v.x, sq0);
            unsafeAtomicAdd(&hist[c * S_SEG + s4.y], v.y); sq1 = fmaf(v.y, v.y, sq1);
            unsafeAtomicAdd(&hist[c * S_SEG + s4.z], v.z); sq2 = fmaf(v.z, v.z, sq2);
            unsafeAtomicAdd(&hist[c * S_SEG + s4.w], v.w); sq3 = fmaf(v.w, v.w, sq3);
        }
        unsafeAtomicAdd(&sq_h[s4.x], sq0);
        unsafeAtomicAdd(&sq_h[s4.y], sq1);
        unsafeAtomicAdd(&sq_h[s4.z], sq2);
        unsafeAtomicAdd(&sq_h[s4.w], sq3);
    }
    __syncthreads();

    for (int i = tid; i < CH_PER * S_SEG; i += BLOCK) {
        const int c = i >> 11, s = i & (S_SEG - 1);
        const float v = hist[i];
        if (v != 0.0f) unsafeAtomicAdd(&sum_g[(size_t)(c0 + c) * S_SEG + s], v);
    }
    for (int i = tid; i < S_SEG; i += BLOCK) {
        const float v = sq_h[i];
        if (v != 0.0f) unsafeAtomicAdd(&sq_g[i], v);
    }
}

__global__ __launch_bounds__(1024) void finalize_kernel(
        const float* __restrict__ sum_g, const float* __restrict__ sq_g,
        const int* __restrict__ cnt_g, float* __restrict__ out) {
    __shared__ float red_l[16], red_c[16];
    const int tid = threadIdx.x;
    float loss = 0.0f, cc = 0.0f;
#pragma unroll
    for (int k = 0; k < 2; ++k) {
        const int s = tid + k * 1024;
        const float cnt = (float)cnt_g[s];
        const float n = fmaxf(cnt, 1.0f);
        float acc = 0.0f;
#pragma unroll 8
        for (int c = 0; c < C_ALL; ++c) {
            const float v = sum_g[c * S_SEG + s];
            acc = fmaf(v, v, acc);
        }
        const float var = sq_g[s] - acc / n;
        loss += (cnt >= 2.0f) ? var / (64.0f * n) : 0.0f;
        cc += (cnt > 0.0f) ? 1.0f : 0.0f;
    }
    for (int off = 32; off; off >>= 1) {
        loss += __shfl_down(loss, off);
        cc += __shfl_down(cc, off);
    }
    const int wave = tid >> 6;
    if ((tid & 63) == 0) { red_l[wave] = loss; red_c[wave] = cc; }
    __syncthreads();
    if (tid < 16) {
        loss = red_l[tid]; cc = red_c[tid];
        for (int off = 8; off; off >>= 1) {
            loss += __shfl_down(loss, off);
            cc += __shfl_down(cc, off);
        }
        if (tid == 0) out[0] = loss / cc;
    }
}

// ============================================================================

extern "C" void kernel_launch(void* const* d_in, const int* in_sizes, int n_in,
                              void* d_out, int out_size, void* d_ws, size_t ws_size,
                              hipStream_t stream) {
    const int* sp = (const int*)d_in[0];        // [2,1024,1024] int32, batch 0 only
    const float* feats = (const float*)d_in[1]; // [2,64,1024,1024] fp32, batch 0 only
    float* ws = (float*)d_ws;

    if (ws_size >= NEEDED_BYTES) {
        // ---- counting-sort path ----
        float* featsS = ws;
        float* sum_sc = ws + W_SUM;
        float* sq_s   = ws + W_SQ;
        int* cnt_q    = (int*)(ws + W_CNTQ);
        int* cnt_tot  = (int*)(ws + W_CNTT);
        int* off_q    = (int*)(ws + W_OFF);
        int* cur_q    = (int*)(ws + W_CUR);

        zero_kernel<<<(ZERO2_WORDS + 255) / 256, 256, 0, stream>>>(ws + W_SUM, ZERO2_WORDS);
        countq_kernel<<<256, 256, 0, stream>>>(sp, cnt_q);
        prefix_kernel<<<1, 1024, 0, stream>>>(cnt_q, cnt_tot, off_q, cur_q);
        for (int q = 0; q < NQ; ++q) {
            scatter_kernel<<<SC_BLOCKS, SC_THREADS, 0, stream>>>(sp, feats, cur_q, featsS, q);
            accumq_kernel<<<S_SEG, 256, 0, stream>>>(featsS, cnt_q, off_q, sum_sc, sq_s, q);
        }
        finalizeq_kernel<<<1, 1024, 0, stream>>>(sum_sc, sq_s, cnt_tot, (float*)d_out);
    } else {
        // ---- fallback: verified LDS-atomic path ----
        float* sum_g = ws;
        float* sq_g = ws + OFF_SQ;
        int* cnt_g = (int*)(ws + OFF_CNT);

        zero_kernel<<<(N_ZERO + 255) / 256, 256, 0, stream>>>(ws, N_ZERO);
        count_kernel<<<256, 256, 0, stream>>>(sp, cnt_g);
        dim3 grid(N_CHUNKS, N_GROUPS);
        accum_kernel<<<grid, BLOCK, 0, stream>>>(sp, feats, sum_g, sq_g);
        finalize_kernel<<<1, 1024, 0, stream>>>(sum_g, sq_g, cnt_g, (float*)d_out);
    }
}